// Round 8
// baseline (527.581 us; speedup 1.0000x reference)
//
#include <hip/hip_runtime.h>
#include <math.h>

#define BB   2
#define SS   2048
#define EE   2048
#define HH   8
#define KVN  4
#define DD   256
#define WINW 1024
#define EPSV 1e-6f
#define NQKV 4096      // q(2048) | k(1024) | v(1024)

using bf16x8 = __attribute__((ext_vector_type(8))) __bf16;
using f32x4  = __attribute__((ext_vector_type(4))) float;

__device__ __forceinline__ unsigned short f2bf(float f) {
    union { float f; unsigned int u; } c; c.f = f;
    unsigned int u = c.u;
    unsigned int r = (u + 0x7FFFu + ((u >> 16) & 1u)) >> 16;   // RTNE
    return (unsigned short)r;
}
__device__ __forceinline__ float bf2f(unsigned short u) {
    union { unsigned int u; float f; } c; c.u = ((unsigned int)u) << 16;
    return c.f;
}

#if defined(__has_builtin)
#if __has_builtin(__builtin_amdgcn_global_load_lds)
#define HAVE_GLL 1
#endif
#endif

#ifdef HAVE_GLL
#define GLOAD_LDS16(gp, sp) __builtin_amdgcn_global_load_lds( \
    (const __attribute__((address_space(1))) unsigned int*)(gp), \
    (__attribute__((address_space(3))) unsigned int*)(sp), 16, 0, 0)
#endif

// ---------------------------------------------------------------------------
// X fp32 -> bf16 (elementwise, 8 per thread)
// ---------------------------------------------------------------------------
__global__ __launch_bounds__(256)
void conv_x(const float* __restrict__ X, unsigned short* __restrict__ Xb)
{
    const size_t i = ((size_t)blockIdx.x * 256 + threadIdx.x) * 8;
    const float4 a = *(const float4*)(X + i);
    const float4 b = *(const float4*)(X + i + 4);
    ushort4 lo, hi;
    lo.x = f2bf(a.x); lo.y = f2bf(a.y); lo.z = f2bf(a.z); lo.w = f2bf(a.w);
    hi.x = f2bf(b.x); hi.y = f2bf(b.y); hi.z = f2bf(b.z); hi.w = f2bf(b.w);
    *(ushort4*)(Xb + i)     = lo;
    *(ushort4*)(Xb + i + 4) = hi;
}

// ---------------------------------------------------------------------------
// Weight fuse+transpose+convert: Wq[K,2048],Wk[K,1024],Wv[K,1024] fp32 ->
// Wt bf16 [N=4096][K=2048] (B^T layout). 64x64 tiles through LDS.
// ---------------------------------------------------------------------------
__global__ __launch_bounds__(256)
void conv_wt(const float* __restrict__ Wq, const float* __restrict__ Wk,
             const float* __restrict__ Wv, unsigned short* __restrict__ Wt)
{
    __shared__ unsigned short Lt[64][72];
    const int k0 = blockIdx.x * 64, n0 = blockIdx.y * 64;
    const int t = threadIdx.x;
    const float* src; int ld, nc;
    if (n0 < 2048)      { src = Wq; ld = 2048; nc = n0; }
    else if (n0 < 3072) { src = Wk; ld = 1024; nc = n0 - 2048; }
    else                { src = Wv; ld = 1024; nc = n0 - 3072; }

#pragma unroll
    for (int p = 0; p < 4; ++p) {
        const int kr = p * 16 + (t >> 4);
        const float4 fv = *(const float4*)(src + (size_t)(k0 + kr) * ld + nc + (t & 15) * 4);
        Lt[kr][(t & 15) * 4 + 0] = f2bf(fv.x);
        Lt[kr][(t & 15) * 4 + 1] = f2bf(fv.y);
        Lt[kr][(t & 15) * 4 + 2] = f2bf(fv.z);
        Lt[kr][(t & 15) * 4 + 3] = f2bf(fv.w);
    }
    __syncthreads();
    const int n = t >> 2, kseg = t & 3;
    unsigned short tmp[16];
#pragma unroll
    for (int j = 0; j < 16; ++j) tmp[j] = Lt[kseg * 16 + j][n];
    unsigned short* dst = Wt + (size_t)(n0 + n) * EE + k0 + kseg * 16;
    *(uint4*)(dst)     = *(uint4*)&tmp[0];
    *(uint4*)(dst + 8) = *(uint4*)&tmp[8];
}

// ---------------------------------------------------------------------------
// Wo transpose+convert: Wo fp32 [K=2048][N=2048] -> Wot bf16 [N][K].
// ---------------------------------------------------------------------------
__global__ __launch_bounds__(256)
void conv_wo(const float* __restrict__ W, unsigned short* __restrict__ Wot)
{
    __shared__ unsigned short Lt[64][72];
    const int k0 = blockIdx.x * 64, n0 = blockIdx.y * 64;
    const int t = threadIdx.x;

#pragma unroll
    for (int p = 0; p < 4; ++p) {
        const int kr = p * 16 + (t >> 4);
        const float4 fv = *(const float4*)(W + (size_t)(k0 + kr) * 2048 + n0 + (t & 15) * 4);
        Lt[kr][(t & 15) * 4 + 0] = f2bf(fv.x);
        Lt[kr][(t & 15) * 4 + 1] = f2bf(fv.y);
        Lt[kr][(t & 15) * 4 + 2] = f2bf(fv.z);
        Lt[kr][(t & 15) * 4 + 3] = f2bf(fv.w);
    }
    __syncthreads();
    const int n = t >> 2, kseg = t & 3;
    unsigned short tmp[16];
#pragma unroll
    for (int j = 0; j < 16; ++j) tmp[j] = Lt[kseg * 16 + j][n];
    unsigned short* dst = Wot + (size_t)(n0 + n) * 2048 + k0 + kseg * 16;
    *(uint4*)(dst)     = *(uint4*)&tmp[0];
    *(uint4*)(dst + 8) = *(uint4*)&tmp[8];
}

// ---------------------------------------------------------------------------
// bf16 MFMA GEMM (m97 structure): C[M,N] = A[M,K] bf16 @ Bt[N,K]^T.
// 128x128 tile, BK=32, 4 waves (2x2 of 64x64), global_load_lds width-16.
// T1 XCD-aware bijective blockIdx swizzle — both grids used here (1024, 512)
// are divisible by 8, so the chunked remap is bijective; consecutive swizzled
// ids share the A row-panel within one XCD L2.
// ---------------------------------------------------------------------------
template <bool F32OUT>
__global__ __launch_bounds__(256)
void gemm_bf16(const unsigned short* __restrict__ A,
               const unsigned short* __restrict__ Bt,
               void* __restrict__ Cv, int M, int N, int K)
{
    __shared__ unsigned short As[128 * 32];
    __shared__ unsigned short Bs[128 * 32];
    const int t = threadIdx.x;
    const int w = t >> 6;
    const int l = t & 63;

    // T1: XCD swizzle (requires nwg % 8 == 0 — holds for all launches here)
    const int nbx = gridDim.x;
    const int nwg = nbx * gridDim.y;
    const int lid = blockIdx.y * nbx + blockIdx.x;
    const int cpx = nwg >> 3;
    const int sid = (lid & 7) * cpx + (lid >> 3);
    const int bm = (sid / nbx) * 128, bn = (sid % nbx) * 128;

    const int wr = w >> 1, wc = w & 1;
    const int l16 = l & 15, lq = l >> 4;

    const int srow = t >> 2;
    const int sk8  = (t & 3) * 8;
    const unsigned short* Ag = A  + (size_t)(bm + srow) * K + sk8;
    const unsigned short* Bg = Bt + (size_t)(bn + srow) * K + sk8;

    f32x4 acc[4][4];
#pragma unroll
    for (int i = 0; i < 4; ++i)
#pragma unroll
        for (int j = 0; j < 4; ++j) acc[i][j] = (f32x4){0.f, 0.f, 0.f, 0.f};

    for (int k0 = 0; k0 < K; k0 += 32) {
        __syncthreads();
#ifdef HAVE_GLL
        GLOAD_LDS16(Ag + k0,            &As[t * 8]);
        GLOAD_LDS16(Ag + k0 + 64 * K,   &As[2048 + t * 8]);
        GLOAD_LDS16(Bg + k0,            &Bs[t * 8]);
        GLOAD_LDS16(Bg + k0 + 64 * K,   &Bs[2048 + t * 8]);
#else
        const uint4 a0 = *(const uint4*)(Ag + k0);
        const uint4 a1 = *(const uint4*)(Ag + k0 + 64 * K);
        const uint4 b0 = *(const uint4*)(Bg + k0);
        const uint4 b1 = *(const uint4*)(Bg + k0 + 64 * K);
        *(uint4*)&As[t * 8]        = a0;
        *(uint4*)&As[2048 + t * 8] = a1;
        *(uint4*)&Bs[t * 8]        = b0;
        *(uint4*)&Bs[2048 + t * 8] = b1;
#endif
        __syncthreads();

        bf16x8 af[4], bf[4];
#pragma unroll
        for (int i = 0; i < 4; ++i)
            af[i] = *(const bf16x8*)&As[(wr * 64 + i * 16 + l16) * 32 + lq * 8];
#pragma unroll
        for (int j = 0; j < 4; ++j)
            bf[j] = *(const bf16x8*)&Bs[(wc * 64 + j * 16 + l16) * 32 + lq * 8];
#pragma unroll
        for (int i = 0; i < 4; ++i)
#pragma unroll
            for (int j = 0; j < 4; ++j)
                acc[i][j] = __builtin_amdgcn_mfma_f32_16x16x32_bf16(af[i], bf[j], acc[i][j], 0, 0, 0);
    }

#pragma unroll
    for (int i = 0; i < 4; ++i)
#pragma unroll
        for (int j = 0; j < 4; ++j)
#pragma unroll
            for (int r = 0; r < 4; ++r) {
                const size_t idx = (size_t)(bm + wr * 64 + i * 16 + lq * 4 + r) * N +
                                   (bn + wc * 64 + j * 16 + l16);
                if constexpr (F32OUT) ((float*)Cv)[idx] = acc[i][j][r];
                else ((unsigned short*)Cv)[idx] = f2bf(acc[i][j][r]);
            }
}

// ---------------------------------------------------------------------------
// Fused RMSNorm (scale=1+w) + RoPE; reads bf16 qkv slice, writes bf16.
// ---------------------------------------------------------------------------
template <int NH, int COLOFF>
__global__ __launch_bounds__(256)
void rmsnorm_rope_qkv(const unsigned short* __restrict__ qkv,
                      unsigned short* __restrict__ out,
                      const float* __restrict__ w,
                      const float* __restrict__ cs, const float* __restrict__ sn,
                      float scale)
{
    const int wv   = threadIdx.x >> 6;
    const int lane = threadIdx.x & 63;
    const int row  = blockIdx.x * 4 + wv;     // m*NH + hh
    const int m    = row / NH;
    const int hh   = row - m * NH;
    const unsigned short* xr = qkv + (size_t)m * NQKV + COLOFF + hh * DD;

    const ushort4 u4 = ((const ushort4*)xr)[lane];
    float4 xv;
    xv.x = bf2f(u4.x); xv.y = bf2f(u4.y); xv.z = bf2f(u4.z); xv.w = bf2f(u4.w);
    float ss = xv.x * xv.x + xv.y * xv.y + xv.z * xv.z + xv.w * xv.w;
#pragma unroll
    for (int d = 1; d < 64; d <<= 1) ss += __shfl_xor(ss, d, 64);
    const float inv = 1.0f / sqrtf(ss * (1.0f / (float)DD) + EPSV);

    const float4 w4 = ((const float4*)w)[lane];
    float4 y;
    y.x = xv.x * inv * (1.f + w4.x);
    y.y = xv.y * inv * (1.f + w4.y);
    y.z = xv.z * inv * (1.f + w4.z);
    y.w = xv.w * inv * (1.f + w4.w);

    __shared__ float4 buf[4][64];
    buf[wv][lane] = y;
    __syncthreads();
    const float4 r0 = buf[wv][(lane < 32) ? (lane + 32) : (lane - 32)];
    float4 rot;
    if (lane < 32) { rot.x = -r0.x; rot.y = -r0.y; rot.z = -r0.z; rot.w = -r0.w; }
    else           { rot = r0; }

    const float4 c4 = ((const float4*)(cs + (size_t)m * DD))[lane];
    const float4 s4 = ((const float4*)(sn + (size_t)m * DD))[lane];
    ushort4 o4;
    o4.x = f2bf((y.x * c4.x + rot.x * s4.x) * scale);
    o4.y = f2bf((y.y * c4.y + rot.y * s4.y) * scale);
    o4.z = f2bf((y.z * c4.z + rot.z * s4.z) * scale);
    o4.w = f2bf((y.w * c4.w + rot.w * s4.w) * scale);
    ((ushort4*)(out + (size_t)row * DD))[lane] = o4;
}

// ---------------------------------------------------------------------------
// V transpose: qkv bf16 v-slice -> Vt bf16 [b,kv,d,s].
// ---------------------------------------------------------------------------
__global__ __launch_bounds__(256)
void v_to_vt(const unsigned short* __restrict__ qkv, unsigned short* __restrict__ Vt)
{
    __shared__ unsigned short Lt[64][72];
    const int s0 = blockIdx.x * 64, d0 = blockIdx.y * 64;
    const int bkv = blockIdx.z;
    const int b = bkv >> 2, kv = bkv & 3;
    const int t = threadIdx.x;

    {
        const int s = t >> 2, seg = t & 3;
        const unsigned short* src = qkv + (size_t)(b * SS + s0 + s) * NQKV +
                                    3072 + kv * DD + d0 + seg * 16;
        *(uint4*)&Lt[s][seg * 16]     = *(const uint4*)(src);
        *(uint4*)&Lt[s][seg * 16 + 8] = *(const uint4*)(src + 8);
    }
    __syncthreads();
    {
        const int d = t >> 2, sseg = t & 3;
        unsigned short tmp[16];
#pragma unroll
        for (int j = 0; j < 16; ++j) tmp[j] = Lt[sseg * 16 + j][d];
        unsigned short* dst = Vt + ((size_t)bkv * DD + d0 + d) * SS + s0 + sseg * 16;
        *(uint4*)(dst)     = *(uint4*)&tmp[0];
        *(uint4*)(dst + 8) = *(uint4*)&tmp[8];
    }
}

// ---------------------------------------------------------------------------
// bf16 MFMA flash attention.
// T14 async-STAGE split — tile t+1's K/V/am global loads are issued into
// REGISTERS before computing tile t; the LDS writes happen after the
// post-compute barrier. HBM latency (~500-900cy) hides under QK^T/softmax/PV.
// Barrier count & placement identical to the verified R6 kernel.
// ---------------------------------------------------------------------------
__global__ __launch_bounds__(256, 2)
void attn_mfma(const unsigned short* __restrict__ Qb,
               const unsigned short* __restrict__ Kb,
               const unsigned short* __restrict__ Vt,
               const int* __restrict__ am, unsigned short* __restrict__ O)
{
    __shared__ unsigned short Ks[32 * 256];    // [j][d], chunk-swizzled
    __shared__ unsigned short Vts[256 * 32];   // [d][j], chunk-swizzled
    __shared__ unsigned short Pl[4][16 * 40];  // per-wave P, row pad 40
    __shared__ int Ams[32];

    const int t = threadIdx.x, w = t >> 6, l = t & 63;
    const int g = l >> 4, q15 = l & 15;
    const int qb0 = blockIdx.x * 64, h = blockIdx.y, b = blockIdx.z;
    const int kvh = h >> 1;
    const int qrow = qb0 + w * 16 + q15;

    bf16x8 qf[8];
    {
        const unsigned short* qp = Qb + ((size_t)(b * SS + qrow) * HH + h) * DD + g * 8;
#pragma unroll
        for (int km = 0; km < 8; ++km) qf[km] = *(const bf16x8*)(qp + km * 32);
    }

    f32x4 oacc[16];
#pragma unroll
    for (int i = 0; i < 16; ++i) oacc[i] = (f32x4){0.f, 0.f, 0.f, 0.f};
    float mrow = -1e30f, lrow = 0.f;

    const int qlo = qb0 + w * 16, qhi = qlo + 15;
    int kstart = qb0 - 1024; if (kstart < 0) kstart = 0;
    const int kend = qb0 + 32;

    const int sj = t >> 3, sc = t & 7;          // K staging: row, 64B chunk
    const int vd0 = t >> 2, vc = t & 3;         // V staging: dim row, 16B chunk

    uint4 kreg[4], vreg[4];
    int amreg = 0;
    const size_t kvbase = (size_t)(b * KVN + kvh);

    // ---- prologue: stage tile kstart (reg -> LDS) ----
    {
        const unsigned short* kp = Kb + ((size_t)(b * SS + kstart + sj) * KVN + kvh) * DD + sc * 32;
#pragma unroll
        for (int i = 0; i < 4; ++i) kreg[i] = *(const uint4*)(kp + i * 8);
#pragma unroll
        for (int it = 0; it < 4; ++it) {
            const int d = it * 64 + vd0;
            vreg[it] = *(const uint4*)(Vt + (kvbase * DD + d) * SS + kstart + vc * 8);
        }
        if (t < 32) amreg = am[b * SS + kstart + t];
    }
#pragma unroll
    for (int i = 0; i < 4; ++i) {
        const int cc = sc * 4 + i;
        *(uint4*)&Ks[sj * 256 + ((cc ^ (sj & 7)) * 8)] = kreg[i];
    }
#pragma unroll
    for (int it = 0; it < 4; ++it) {
        const int d = it * 64 + vd0;
        *(uint4*)&Vts[d * 32 + ((vc ^ (d & 3)) * 8)] = vreg[it];
    }
    if (t < 32) Ams[t] = amreg;
    __syncthreads();

    for (int k0 = kstart; k0 <= kend; k0 += 32) {
        const int kn = k0 + 32;
        const bool hasNext = (kn <= kend);

        // ---- issue next tile's global loads (latency hidden under compute) ----
        if (hasNext) {
            const unsigned short* kp = Kb + ((size_t)(b * SS + kn + sj) * KVN + kvh) * DD + sc * 32;
#pragma unroll
            for (int i = 0; i < 4; ++i) kreg[i] = *(const uint4*)(kp + i * 8);
#pragma unroll
            for (int it = 0; it < 4; ++it) {
                const int d = it * 64 + vd0;
                vreg[it] = *(const uint4*)(Vt + (kvbase * DD + d) * SS + kn + vc * 8);
            }
            if (t < 32) amreg = am[b * SS + kn + t];
        }

        // ---- compute current tile from LDS ----
        if (k0 <= qhi && k0 + 31 >= qlo - (WINW - 1)) {
            float pv[8];
            int   okf[8];
            float tmax = -1e30f;
#pragma unroll
            for (int jb = 0; jb < 2; ++jb) {
                f32x4 sacc = (f32x4){0.f, 0.f, 0.f, 0.f};
                const int krow = jb * 16 + q15;
                const unsigned short* kbase = &Ks[krow * 256];
                const int kx = krow & 7;
#pragma unroll
                for (int km = 0; km < 8; ++km) {
                    const bf16x8 kf = *(const bf16x8*)(kbase + (((km * 4 + g) ^ kx) * 8));
                    sacc = __builtin_amdgcn_mfma_f32_16x16x32_bf16(kf, qf[km], sacc, 0, 0, 0);
                }
#pragma unroll
                for (int r = 0; r < 4; ++r) {
                    const int jgl = k0 + jb * 16 + g * 4 + r;
                    const bool ok = (jgl <= qrow) && (qrow - jgl < WINW) &&
                                    (Ams[jb * 16 + g * 4 + r] != 0);
                    const float val = ok ? sacc[r] : -1e30f;
                    okf[jb * 4 + r] = ok;
                    pv[jb * 4 + r] = val;
                    tmax = fmaxf(tmax, val);
                }
            }
            tmax = fmaxf(tmax, __shfl_xor(tmax, 16, 64));
            tmax = fmaxf(tmax, __shfl_xor(tmax, 32, 64));
            const float mnew = fmaxf(mrow, tmax);
            const float corr = __expf(mrow - mnew);
            float ps = 0.f;
#pragma unroll
            for (int i = 0; i < 8; ++i) {
                const float p = okf[i] ? __expf(pv[i] - mnew) : 0.f;
                pv[i] = p; ps += p;
            }
            ps += __shfl_xor(ps, 16, 64);
            ps += __shfl_xor(ps, 32, 64);
            lrow = lrow * corr + ps;
            mrow = mnew;

            unsigned short* Pw = &Pl[w][0];
#pragma unroll
            for (int jb = 0; jb < 2; ++jb) {
                const unsigned int u0 = (unsigned int)f2bf(pv[jb * 4 + 0]) |
                                        ((unsigned int)f2bf(pv[jb * 4 + 1]) << 16);
                const unsigned int u1 = (unsigned int)f2bf(pv[jb * 4 + 2]) |
                                        ((unsigned int)f2bf(pv[jb * 4 + 3]) << 16);
                *(unsigned int*)&Pw[q15 * 40 + jb * 16 + g * 4]     = u0;
                *(unsigned int*)&Pw[q15 * 40 + jb * 16 + g * 4 + 2] = u1;
            }

            if (__any(corr != 1.0f)) {
                const float c0 = __shfl(corr, g * 4 + 0, 64);
                const float c1 = __shfl(corr, g * 4 + 1, 64);
                const float c2 = __shfl(corr, g * 4 + 2, 64);
                const float c3 = __shfl(corr, g * 4 + 3, 64);
#pragma unroll
                for (int dm = 0; dm < 16; ++dm) {
                    oacc[dm][0] *= c0; oacc[dm][1] *= c1;
                    oacc[dm][2] *= c2; oacc[dm][3] *= c3;
                }
            }

            asm volatile("s_waitcnt lgkmcnt(0)" ::: "memory");
            const bf16x8 pa = *(const bf16x8*)&Pw[q15 * 40 + g * 8];
#pragma unroll
            for (int dm = 0; dm < 16; ++dm) {
                const int d = dm * 16 + q15;
                const bf16x8 vf = *(const bf16x8*)&Vts[d * 32 + ((g ^ (d & 3)) * 8)];
                oacc[dm] = __builtin_amdgcn_mfma_f32_16x16x32_bf16(pa, vf, oacc[dm], 0, 0, 0);
            }
        }
        __syncthreads();                       // all waves done reading LDS tile t

        // ---- write next tile regs -> LDS ----
        if (hasNext) {
#pragma unroll
            for (int i = 0; i < 4; ++i) {
                const int cc = sc * 4 + i;
                *(uint4*)&Ks[sj * 256 + ((cc ^ (sj & 7)) * 8)] = kreg[i];
            }
#pragma unroll
            for (int it = 0; it < 4; ++it) {
                const int d = it * 64 + vd0;
                *(uint4*)&Vts[d * 32 + ((vc ^ (d & 3)) * 8)] = vreg[it];
            }
            if (t < 32) Ams[t] = amreg;
        }
        __syncthreads();                       // tile t+1 visible
    }

    float invl[4];
#pragma unroll
    for (int r = 0; r < 4; ++r) invl[r] = 1.0f / __shfl(lrow, g * 4 + r, 64);
#pragma unroll
    for (int dm = 0; dm < 16; ++dm) {
#pragma unroll
        for (int r = 0; r < 4; ++r) {
            const int qo = qb0 + w * 16 + g * 4 + r;
            O[((size_t)(b * SS + qo) * HH + h) * DD + dm * 16 + q15] =
                f2bf(oacc[dm][r] * invl[r]);
        }
    }
}

// ---------------------------------------------------------------------------
// Launch. Workspace (64 MiB, phase-reuse):
//   [ 0,16)  Xb bf16              -> Qb bf16 (after QKV GEMM)
//   [16,24)  Wt lower             -> Kb bf16
//   [24,32)  Wt upper             -> Vt bf16
//   [32,64)  qkv bf16 [4096][4096] -> Wot bf16 [32,40) + Ob bf16 [40,56)
//            (conv_wo runs AFTER norms+v_to_vt free the qkv region)
// ---------------------------------------------------------------------------
extern "C" void kernel_launch(void* const* d_in, const int* in_sizes, int n_in,
                              void* d_out, int out_size, void* d_ws, size_t ws_size,
                              hipStream_t stream)
{
    (void)in_sizes; (void)n_in; (void)out_size; (void)ws_size;

    const float* X  = (const float*)d_in[0];
    const float* cs = (const float*)d_in[1];
    const float* sn = (const float*)d_in[2];
    const int*   am = (const int*)d_in[3];
    const float* Wq = (const float*)d_in[4];
    const float* Wk = (const float*)d_in[5];
    const float* Wv = (const float*)d_in[6];
    const float* Wo = (const float*)d_in[7];
    const float* qw = (const float*)d_in[8];
    const float* kw = (const float*)d_in[9];
    float* out = (float*)d_out;

    char* ws = (char*)d_ws;
    unsigned short* Xb  = (unsigned short*)(ws);
    unsigned short* Qb  = (unsigned short*)(ws);                            // aliases Xb
    unsigned short* Wt  = (unsigned short*)(ws + (size_t)16 * 1024 * 1024);
    unsigned short* Kb  = (unsigned short*)(ws + (size_t)16 * 1024 * 1024); // aliases Wt
    unsigned short* Vt  = (unsigned short*)(ws + (size_t)24 * 1024 * 1024);
    unsigned short* qkv = (unsigned short*)(ws + (size_t)32 * 1024 * 1024);
    unsigned short* Wot = (unsigned short*)(ws + (size_t)32 * 1024 * 1024); // after qkv dead
    unsigned short* Ob  = (unsigned short*)(ws + (size_t)40 * 1024 * 1024); // after qkv dead

    const int M = BB * SS;   // 4096
    dim3 blk(256);

    // bf16 conversions (inputs)
    conv_x <<<dim3((M * EE) / (256 * 8)), blk, 0, stream>>>(X, Xb);
    conv_wt<<<dim3(EE / 64, NQKV / 64), blk, 0, stream>>>(Wq, Wk, Wv, Wt);

    // fused QKV projection (bf16 MFMA) -> qkv bf16
    gemm_bf16<false><<<dim3(NQKV / 128, M / 128), blk, 0, stream>>>(Xb, Wt, qkv, M, NQKV, EE);

    // norms (q-scale folded) + V transpose; these consume qkv
    rmsnorm_rope_qkv<KVN, 2048><<<dim3(M * KVN / 4), blk, 0, stream>>>(qkv, Kb, kw, cs, sn, 1.0f);
    rmsnorm_rope_qkv<HH, 0>    <<<dim3(M * HH  / 4), blk, 0, stream>>>(qkv, Qb, qw, cs, sn, 0.0625f);
    v_to_vt<<<dim3(SS / 64, DD / 64, BB * KVN), blk, 0, stream>>>(qkv, Vt);

    // qkv now dead: convert Wo into its region
    conv_wo<<<dim3(2048 / 64, 2048 / 64), blk, 0, stream>>>(Wo, Wot);

    // attention (bf16 MFMA) -> bf16 O
    attn_mfma<<<dim3(SS / 64, HH, BB), blk, 0, stream>>>(Qb, Kb, Vt, am, Ob);

    // output projection (bf16 MFMA, fp32 out)
    gemm_bf16<true><<<dim3(EE / 128, M / 128), blk, 0, stream>>>(Ob, Wot, out, M, EE, EE);
}